// Round 1
// baseline (416.347 us; speedup 1.0000x reference)
//
#include <hip/hip_runtime.h>
#include <hip/hip_bf16.h>
#include <cstdint>
#include <cstddef>

// ---------- problem constants ----------
static constexpr int Bn = 4, Tn = 2048, Cn = 1024, Hn = 16, HD = 64;
static constexpr int Mn = Bn * Tn;            // 8192 tokens
static constexpr float SCALE = 0.03125f;      // C^-0.5 = 1/32 (full embed dim, per reference quirk)

typedef __attribute__((ext_vector_type(8))) short s16x8;
typedef __attribute__((ext_vector_type(4))) float f32x4;

#define DEVFN __device__ __forceinline__

DEVFN unsigned short f2bf(float f) {
  union { float f; unsigned u; } v; v.f = f;
  unsigned r = v.u + 0x7fffu + ((v.u >> 16) & 1u);   // RNE
  return (unsigned short)(r >> 16);
}

DEVFN void gload_lds16(const void* g, void* l) {
  __builtin_amdgcn_global_load_lds(
      (const __attribute__((address_space(1))) void*)g,
      (__attribute__((address_space(3))) void*)l, 16, 0, 0);
}

// ---------- fp32 -> bf16 convert ----------
__global__ __launch_bounds__(256) void k_cvt(const float* __restrict__ in,
                                             unsigned short* __restrict__ out, int n4) {
  int i = blockIdx.x * 256 + threadIdx.x;
  if (i >= n4) return;
  float4 v = reinterpret_cast<const float4*>(in)[i];
  ushort4 o;
  o.x = f2bf(v.x); o.y = f2bf(v.y); o.z = f2bf(v.z); o.w = f2bf(v.w);
  reinterpret_cast<ushort4*>(out)[i] = o;
}

// ---------- mask bit-pack: [T][T] int32 -> [T][T/32] u32 ----------
__global__ __launch_bounds__(256) void k_pack(const int* __restrict__ mask,
                                              unsigned* __restrict__ bits) {
  int i = blockIdx.x * 256 + threadIdx.x;          // element index over T*T
  unsigned long long b = __ballot(mask[i] != 0);
  int lane = threadIdx.x & 63;
  if (lane == 0)        bits[i >> 5] = (unsigned)b;
  else if (lane == 32)  bits[i >> 5] = (unsigned)(b >> 32);
}

// ---------- 128x128 GEMM, C[m,n] = sum_k A[m,k]*Bt[n,k]  (both K-major bf16) ----------
template <bool F32OUT>
__global__ __launch_bounds__(256) void k_gemm(const unsigned short* __restrict__ A,
                                              const unsigned short* __restrict__ Bt,
                                              void* __restrict__ Cv,
                                              const float* __restrict__ bias,
                                              int M, int N, int K) {
  __shared__ __align__(16) char As[128 * 64 * 2];
  __shared__ __align__(16) char Bs[128 * 64 * 2];
  const int tid = threadIdx.x, lane = tid & 63, wid = tid >> 6;
  const int l15 = lane & 15, lg = lane >> 4;
  const int wm = (wid >> 1) * 64, wn = (wid & 1) * 64;
  const int m0 = blockIdx.y * 128, n0 = blockIdx.x * 128;

  f32x4 acc[4][4];
#pragma unroll
  for (int i = 0; i < 4; ++i)
#pragma unroll
    for (int j = 0; j < 4; ++j) acc[i][j] = f32x4{0.f, 0.f, 0.f, 0.f};

  for (int k0 = 0; k0 < K; k0 += 64) {
#pragma unroll
    for (int it = 0; it < 4; ++it) {
      int chunk = it * 256 + tid;
      int row = chunk >> 3;
      int kg = (chunk & 7) ^ (row & 7);          // inverse-swizzled SOURCE (rule 21)
      gload_lds16(A + (size_t)(m0 + row) * K + k0 + kg * 8,
                  As + (it * 256 + wid * 64) * 16);
      gload_lds16(Bt + (size_t)(n0 + row) * K + k0 + kg * 8,
                  Bs + (it * 256 + wid * 64) * 16);
    }
    __syncthreads();
#pragma unroll
    for (int kk = 0; kk < 64; kk += 32) {
      s16x8 a[4], b[4];
#pragma unroll
      for (int i = 0; i < 4; ++i) {
        int ra = wm + i * 16 + l15;
        a[i] = *(const s16x8*)(As + ra * 128 + (((kk + lg * 8) * 2) ^ ((ra & 7) << 4)));
        int rb = wn + i * 16 + l15;
        b[i] = *(const s16x8*)(Bs + rb * 128 + (((kk + lg * 8) * 2) ^ ((rb & 7) << 4)));
      }
#pragma unroll
      for (int i = 0; i < 4; ++i)
#pragma unroll
        for (int j = 0; j < 4; ++j)
          acc[i][j] = __builtin_amdgcn_mfma_f32_16x16x32_bf16(a[i], b[j], acc[i][j], 0, 0, 0);
    }
    __syncthreads();
  }
#pragma unroll
  for (int i = 0; i < 4; ++i)
#pragma unroll
    for (int j = 0; j < 4; ++j)
#pragma unroll
      for (int q = 0; q < 4; ++q) {
        int r = m0 + wm + i * 16 + lg * 4 + q;   // C/D layout: col=lane&15, row=(lane>>4)*4+reg
        int c = n0 + wn + j * 16 + l15;
        float v = acc[i][j][q];
        if (F32OUT) ((float*)Cv)[(size_t)r * N + c] = v + bias[c];
        else        ((unsigned short*)Cv)[(size_t)r * N + c] = f2bf(v);
      }
}

// ---------- fused attention: per block = (q-tile of 128 rows) x (one b,h) ----------
__global__ __launch_bounds__(256) void k_attn(const unsigned short* __restrict__ Qg,
                                              const unsigned short* __restrict__ Kg,
                                              const unsigned short* __restrict__ Vg,
                                              const unsigned* __restrict__ mbits,
                                              unsigned short* __restrict__ Og) {
  __shared__ __align__(16) char Qs[128 * 128];    // 128 rows x 64 bf16, swizzled
  __shared__ __align__(16) char Ks[64 * 128];     // 64 rows x 64 bf16
  __shared__ __align__(16) char Vts[64 * 128];    // transposed V: row=d, col=kpos
  __shared__ __align__(16) char Ps[4][32 * 128];  // per-wave P tile 32x64 bf16
  __shared__ unsigned Mw[128 * 2];                // mask words for this (qtile,ktile)

  const int tid = threadIdx.x, lane = tid & 63, wid = tid >> 6;
  const int l15 = lane & 15, lg = lane >> 4;
  const int qt = blockIdx.x, bh = blockIdx.y;
  const int b = bh >> 4, h = bh & 15;
  const size_t rowbase = (size_t)b * Tn;
  const int cbase = h * 64;

  // stage Q tile once (pre-swizzled source -> linear LDS dest)
#pragma unroll
  for (int it = 0; it < 4; ++it) {
    int chunk = it * 256 + tid;
    int row = chunk >> 3;
    int kg = (chunk & 7) ^ (row & 7);
    gload_lds16(Qg + (rowbase + qt * 128 + row) * Cn + cbase + kg * 8,
                Qs + (it * 256 + wid * 64) * 16);
  }

  f32x4 oacc[2][4];
#pragma unroll
  for (int m = 0; m < 2; ++m)
#pragma unroll
    for (int n = 0; n < 4; ++n) oacc[m][n] = f32x4{0.f, 0.f, 0.f, 0.f};
  float mrun[8], lrun[8];
#pragma unroll
  for (int i = 0; i < 8; ++i) { mrun[i] = -1e30f; lrun[i] = 0.0f; }

  char* Pw = Ps[wid];

  for (int kt = 0; kt < Tn / 64; ++kt) {
    // stage K tile
#pragma unroll
    for (int it = 0; it < 2; ++it) {
      int chunk = it * 256 + tid;
      int row = chunk >> 3;
      int kg = (chunk & 7) ^ (row & 7);
      gload_lds16(Kg + (rowbase + kt * 64 + row) * Cn + cbase + kg * 8,
                  Ks + (it * 256 + wid * 64) * 16);
    }
    // stage V transposed (reg-staged; swizzled 2B writes)
    {
      int r = tid >> 2;                 // kpos 0..63
      int c0 = (tid & 3) * 16;          // d start
      const unsigned short* src = Vg + (rowbase + kt * 64 + r) * Cn + cbase + c0;
      s16x8 v0 = *(const s16x8*)(src);
      s16x8 v1 = *(const s16x8*)(src + 8);
#pragma unroll
      for (int e = 0; e < 8; ++e) {
        int d = c0 + e;
        *(short*)(Vts + d * 128 + ((r * 2) ^ ((d & 7) << 4))) = v0[e];
        int d2 = c0 + 8 + e;
        *(short*)(Vts + d2 * 128 + ((r * 2) ^ ((d2 & 7) << 4))) = v1[e];
      }
    }
    // stage mask words: Mw[qrow][w], w = ktile-local word 0/1
    {
      int qr = tid >> 1, w = tid & 1;
      Mw[qr * 2 + w] = mbits[(size_t)(qt * 128 + qr) * (Tn / 32) + kt * 2 + w];
    }
    __syncthreads();

    // ---- S = Q K^T ----
    f32x4 sacc[2][4];
#pragma unroll
    for (int m = 0; m < 2; ++m)
#pragma unroll
      for (int n = 0; n < 4; ++n) sacc[m][n] = f32x4{0.f, 0.f, 0.f, 0.f};
#pragma unroll
    for (int kk = 0; kk < 64; kk += 32) {
      s16x8 a[2], bb[4];
#pragma unroll
      for (int m = 0; m < 2; ++m) {
        int ra = wid * 32 + m * 16 + l15;
        a[m] = *(const s16x8*)(Qs + ra * 128 + (((kk + lg * 8) * 2) ^ ((ra & 7) << 4)));
      }
#pragma unroll
      for (int n = 0; n < 4; ++n) {
        int rb = n * 16 + l15;
        bb[n] = *(const s16x8*)(Ks + rb * 128 + (((kk + lg * 8) * 2) ^ ((rb & 7) << 4)));
      }
#pragma unroll
      for (int m = 0; m < 2; ++m)
#pragma unroll
        for (int n = 0; n < 4; ++n)
          sacc[m][n] = __builtin_amdgcn_mfma_f32_16x16x32_bf16(a[m], bb[n], sacc[m][n], 0, 0, 0);
    }

    // ---- mask (zero-fill quirk) + online softmax + write P ----
#pragma unroll
    for (int m = 0; m < 2; ++m) {
#pragma unroll
      for (int q = 0; q < 4; ++q) {
        int rloc = m * 16 + lg * 4 + q;     // wave-local q row
        int qr = wid * 32 + rloc;           // block-local
        unsigned w0 = Mw[qr * 2], w1 = Mw[qr * 2 + 1];
        float s[4];
#pragma unroll
        for (int n = 0; n < 4; ++n) {
          int kl = n * 16 + l15;
          unsigned wm_ = (n < 2) ? w0 : w1;
          s[n] = ((wm_ >> (kl & 31)) & 1u) ? sacc[m][n][q] * SCALE : 0.0f;
        }
        float mx = fmaxf(fmaxf(s[0], s[1]), fmaxf(s[2], s[3]));
#pragma unroll
        for (int d = 1; d < 16; d <<= 1) mx = fmaxf(mx, __shfl_xor(mx, d));
        int si = m * 4 + q;
        float mold = mrun[si];
        float mnew = fmaxf(mold, mx);
        float corr = __expf(mold - mnew);
        float p[4], ps = 0.0f;
#pragma unroll
        for (int n = 0; n < 4; ++n) { p[n] = __expf(s[n] - mnew); ps += p[n]; }
#pragma unroll
        for (int d = 1; d < 16; d <<= 1) ps += __shfl_xor(ps, d);
        lrun[si] = lrun[si] * corr + ps;
        mrun[si] = mnew;
#pragma unroll
        for (int n = 0; n < 4; ++n) oacc[m][n][q] *= corr;
#pragma unroll
        for (int n = 0; n < 4; ++n) {
          int col = n * 16 + l15;
          *(short*)(Pw + rloc * 128 + ((col * 2) ^ ((rloc & 7) << 4))) = (short)f2bf(p[n]);
        }
      }
    }

    // ---- O += P V ----
#pragma unroll
    for (int kk = 0; kk < 64; kk += 32) {
      s16x8 pa[2], vb[4];
#pragma unroll
      for (int m = 0; m < 2; ++m) {
        int rp = m * 16 + l15;
        pa[m] = *(const s16x8*)(Pw + rp * 128 + (((kk + lg * 8) * 2) ^ ((rp & 7) << 4)));
      }
#pragma unroll
      for (int n = 0; n < 4; ++n) {
        int rv = n * 16 + l15;
        vb[n] = *(const s16x8*)(Vts + rv * 128 + (((kk + lg * 8) * 2) ^ ((rv & 7) << 4)));
      }
#pragma unroll
      for (int m = 0; m < 2; ++m)
#pragma unroll
        for (int n = 0; n < 4; ++n)
          oacc[m][n] = __builtin_amdgcn_mfma_f32_16x16x32_bf16(pa[m], vb[n], oacc[m][n], 0, 0, 0);
    }
    __syncthreads();
  }

  // epilogue: divide by l, write bf16 attention output [m][c]
#pragma unroll
  for (int m = 0; m < 2; ++m)
#pragma unroll
    for (int q = 0; q < 4; ++q) {
      int si = m * 4 + q;
      float inv = 1.0f / lrun[si];
      int rg = qt * 128 + wid * 32 + m * 16 + lg * 4 + q;
#pragma unroll
      for (int n = 0; n < 4; ++n)
        Og[(rowbase + rg) * Cn + cbase + n * 16 + l15] = f2bf(oacc[m][n][q] * inv);
    }
}

// ---------- host ----------
extern "C" void kernel_launch(void* const* d_in, const int* in_sizes, int n_in,
                              void* d_out, int out_size, void* d_ws, size_t ws_size,
                              hipStream_t stream) {
  (void)in_sizes; (void)n_in; (void)out_size; (void)ws_size;
  const float* query = (const float*)d_in[0];
  const float* key_  = (const float*)d_in[1];
  const float* value = (const float*)d_in[2];
  const int*   mask  = (const int*)d_in[3];
  const float* Wq = (const float*)d_in[4];
  const float* Wk = (const float*)d_in[5];
  const float* Wv = (const float*)d_in[6];
  const float* Wp = (const float*)d_in[7];
  const float* bp = (const float*)d_in[8];

  char* ws = (char*)d_ws;
  const size_t SX = (size_t)Mn * Cn * 2;   // 16 MiB
  const size_t SW = (size_t)Cn * Cn * 2;   // 2 MiB
  unsigned short* Xq  = (unsigned short*)(ws);
  unsigned short* Xk  = (unsigned short*)(ws + SX);
  unsigned short* Xv  = (unsigned short*)(ws + 2 * SX);
  unsigned short* Wqb = (unsigned short*)(ws + 3 * SX);
  unsigned short* Wkb = (unsigned short*)(ws + 3 * SX + SW);
  unsigned short* Wvb = (unsigned short*)(ws + 3 * SX + 2 * SW);
  unsigned short* Wpb = (unsigned short*)(ws + 3 * SX + 3 * SW);
  unsigned short* Qb  = (unsigned short*)(ws + 3 * SX + 4 * SW);
  unsigned short* Kb  = (unsigned short*)(ws + 4 * SX + 4 * SW);
  unsigned short* Vb  = (unsigned short*)(ws + 5 * SX + 4 * SW);
  unsigned*       mb  = (unsigned*)(ws + 6 * SX + 4 * SW);
  unsigned short* AO  = Xq;  // alias: Xq dead after Q-projection GEMM

  const int nX4 = Mn * Cn / 4, nW4 = Cn * Cn / 4;
  k_cvt<<<dim3(nX4 / 256), dim3(256), 0, stream>>>(query, Xq, nX4);
  k_cvt<<<dim3(nX4 / 256), dim3(256), 0, stream>>>(key_,  Xk, nX4);
  k_cvt<<<dim3(nX4 / 256), dim3(256), 0, stream>>>(value, Xv, nX4);
  k_cvt<<<dim3(nW4 / 256), dim3(256), 0, stream>>>(Wq, Wqb, nW4);
  k_cvt<<<dim3(nW4 / 256), dim3(256), 0, stream>>>(Wk, Wkb, nW4);
  k_cvt<<<dim3(nW4 / 256), dim3(256), 0, stream>>>(Wv, Wvb, nW4);
  k_cvt<<<dim3(nW4 / 256), dim3(256), 0, stream>>>(Wp, Wpb, nW4);
  k_pack<<<dim3((Tn * Tn) / 256), dim3(256), 0, stream>>>(mask, mb);

  dim3 gg(Cn / 128, Mn / 128);  // (8, 64)
  k_gemm<false><<<gg, dim3(256), 0, stream>>>(Xq, Wqb, Qb, nullptr, Mn, Cn, Cn);
  k_gemm<false><<<gg, dim3(256), 0, stream>>>(Xk, Wkb, Kb, nullptr, Mn, Cn, Cn);
  k_gemm<false><<<gg, dim3(256), 0, stream>>>(Xv, Wvb, Vb, nullptr, Mn, Cn, Cn);

  k_attn<<<dim3(Tn / 128, Bn * Hn), dim3(256), 0, stream>>>(Qb, Kb, Vb, mb, AO);

  k_gemm<true><<<gg, dim3(256), 0, stream>>>(AO, Wpb, d_out, bp, Mn, Cn, Cn);
}

// Round 5
// 321.231 us; speedup vs baseline: 1.2961x; 1.2961x over previous
//
#include <hip/hip_runtime.h>
#include <hip/hip_bf16.h>
#include <cstdint>
#include <cstddef>

// ---------- problem constants ----------
static constexpr int Bn = 4, Tn = 2048, Cn = 1024, Hn = 16, HD = 64;
static constexpr int Mn = Bn * Tn;            // 8192 tokens
static constexpr float SCALE = 0.03125f;      // C^-0.5 = 1/32 (full embed dim, per reference quirk)

typedef __attribute__((ext_vector_type(8))) short s16x8;
typedef __attribute__((ext_vector_type(4))) float f32x4;

#define DEVFN __device__ __forceinline__

DEVFN unsigned short f2bf(float f) {
  union { float f; unsigned u; } v; v.f = f;
  unsigned r = v.u + 0x7fffu + ((v.u >> 16) & 1u);   // RNE
  return (unsigned short)(r >> 16);
}

DEVFN void gload_lds16(const void* g, void* l) {
  __builtin_amdgcn_global_load_lds(
      (const __attribute__((address_space(1))) void*)g,
      (__attribute__((address_space(3))) void*)l, 16, 0, 0);
}

// ---------- fp32 -> bf16 convert ----------
__global__ __launch_bounds__(256) void k_cvt(const float* __restrict__ in,
                                             unsigned short* __restrict__ out, int n4) {
  int i = blockIdx.x * 256 + threadIdx.x;
  if (i >= n4) return;
  float4 v = reinterpret_cast<const float4*>(in)[i];
  ushort4 o;
  o.x = f2bf(v.x); o.y = f2bf(v.y); o.z = f2bf(v.z); o.w = f2bf(v.w);
  reinterpret_cast<ushort4*>(out)[i] = o;
}

// ---------- mask bit-pack: [T][T] int32 -> [T][T/32] u32 ----------
__global__ __launch_bounds__(256) void k_pack(const int* __restrict__ mask,
                                              unsigned* __restrict__ bits) {
  int i = blockIdx.x * 256 + threadIdx.x;          // element index over T*T
  unsigned long long b = __ballot(mask[i] != 0);
  int lane = threadIdx.x & 63;
  if (lane == 0)        bits[i >> 5] = (unsigned)b;
  else if (lane == 32)  bits[i >> 5] = (unsigned)(b >> 32);
}

// ---------- 128x128 GEMM, C[m,n] = sum_k A[m,k]*Bt[n,k]  (both K-major bf16) ----------
template <bool F32OUT>
__global__ __launch_bounds__(256) void k_gemm(const unsigned short* __restrict__ A,
                                              const unsigned short* __restrict__ Bt,
                                              void* __restrict__ Cv,
                                              const float* __restrict__ bias,
                                              int M, int N, int K) {
  __shared__ __align__(16) char As[128 * 64 * 2];
  __shared__ __align__(16) char Bs[128 * 64 * 2];
  const int tid = threadIdx.x, lane = tid & 63, wid = tid >> 6;
  const int l15 = lane & 15, lg = lane >> 4;
  const int wm = (wid >> 1) * 64, wn = (wid & 1) * 64;
  const int m0 = blockIdx.y * 128, n0 = blockIdx.x * 128;

  f32x4 acc[4][4];
#pragma unroll
  for (int i = 0; i < 4; ++i)
#pragma unroll
    for (int j = 0; j < 4; ++j) acc[i][j] = f32x4{0.f, 0.f, 0.f, 0.f};

  for (int k0 = 0; k0 < K; k0 += 64) {
#pragma unroll
    for (int it = 0; it < 4; ++it) {
      int chunk = it * 256 + tid;
      int row = chunk >> 3;
      int kg = (chunk & 7) ^ (row & 7);          // inverse-swizzled SOURCE (rule 21)
      gload_lds16(A + (size_t)(m0 + row) * K + k0 + kg * 8,
                  As + (it * 256 + wid * 64) * 16);
      gload_lds16(Bt + (size_t)(n0 + row) * K + k0 + kg * 8,
                  Bs + (it * 256 + wid * 64) * 16);
    }
    __syncthreads();
#pragma unroll
    for (int kk = 0; kk < 64; kk += 32) {
      s16x8 a[4], b[4];
#pragma unroll
      for (int i = 0; i < 4; ++i) {
        int ra = wm + i * 16 + l15;
        a[i] = *(const s16x8*)(As + ra * 128 + (((kk + lg * 8) * 2) ^ ((ra & 7) << 4)));
        int rb = wn + i * 16 + l15;
        b[i] = *(const s16x8*)(Bs + rb * 128 + (((kk + lg * 8) * 2) ^ ((rb & 7) << 4)));
      }
#pragma unroll
      for (int i = 0; i < 4; ++i)
#pragma unroll
        for (int j = 0; j < 4; ++j)
          acc[i][j] = __builtin_amdgcn_mfma_f32_16x16x32_bf16(a[i], b[j], acc[i][j], 0, 0, 0);
    }
    __syncthreads();
  }
#pragma unroll
  for (int i = 0; i < 4; ++i)
#pragma unroll
    for (int j = 0; j < 4; ++j)
#pragma unroll
      for (int q = 0; q < 4; ++q) {
        int r = m0 + wm + i * 16 + lg * 4 + q;   // C/D layout: col=lane&15, row=(lane>>4)*4+reg
        int c = n0 + wn + j * 16 + l15;
        float v = acc[i][j][q];
        if (F32OUT) ((float*)Cv)[(size_t)r * N + c] = v + bias[c];
        else        ((unsigned short*)Cv)[(size_t)r * N + c] = f2bf(v);
      }
}

// ---------- fused attention v3: R1 layout + no-max softmax + deferred denominator ----------
__global__ __launch_bounds__(256) void k_attn(const unsigned short* __restrict__ Qg,
                                              const unsigned short* __restrict__ Kg,
                                              const unsigned short* __restrict__ Vg,
                                              const unsigned* __restrict__ mbits,
                                              unsigned short* __restrict__ Og) {
  __shared__ __align__(16) char Qs[128 * 128];    // 128 q-rows x 64 d, swizzled
  __shared__ __align__(16) char Ks[64 * 128];     // 64 k-rows x 64 d, swizzled
  __shared__ __align__(16) char Vts[64 * 128];    // transposed V: row=d, col=kpos
  __shared__ __align__(16) char Ps[4][32 * 128];  // per-wave P: 32 q x 64 k bf16, swizzled
  __shared__ unsigned Mw[128 * 2];                // mask words for this (qtile,ktile)

  const int tid = threadIdx.x, lane = tid & 63, wid = tid >> 6;
  const int l15 = lane & 15, lg = lane >> 4;
  const int qt = blockIdx.x, bh = blockIdx.y;
  const int b = bh >> 4, h = bh & 15;
  const size_t rowbase = (size_t)b * Tn;
  const int cbase = h * 64;

  // stage Q tile once (pre-swizzled source -> linear LDS dest)
#pragma unroll
  for (int it = 0; it < 4; ++it) {
    int chunk = it * 256 + tid;
    int row = chunk >> 3;
    int kg = (chunk & 7) ^ (row & 7);
    gload_lds16(Qg + (rowbase + qt * 128 + row) * Cn + cbase + kg * 8,
                Qs + (it * 256 + wid * 64) * 16);
  }

  f32x4 oacc[2][4];                       // [m][n]; O row = m*16+lg*4+reg, col = n*16+l15
#pragma unroll
  for (int m = 0; m < 2; ++m)
#pragma unroll
    for (int n = 0; n < 4; ++n) oacc[m][n] = f32x4{0.f, 0.f, 0.f, 0.f};
  float lsum[8];                          // per-thread partial denominators, row si = m*4+q
#pragma unroll
  for (int i = 0; i < 8; ++i) lsum[i] = 0.0f;

  char* Pw = Ps[wid];

  for (int kt = 0; kt < Tn / 64; ++kt) {
    // stage K tile (global_load_lds, pre-swizzled source)
#pragma unroll
    for (int it = 0; it < 2; ++it) {
      int chunk = it * 256 + tid;
      int row = chunk >> 3;
      int kg = (chunk & 7) ^ (row & 7);
      gload_lds16(Kg + (rowbase + kt * 64 + row) * Cn + cbase + kg * 8,
                  Ks + (it * 256 + wid * 64) * 16);
    }
    // stage V transposed (reg-staged; swizzled 2B writes)
    {
      int r = tid >> 2;                 // kpos 0..63
      int c0 = (tid & 3) * 16;          // d start
      const unsigned short* src = Vg + (rowbase + kt * 64 + r) * Cn + cbase + c0;
      s16x8 v0 = *(const s16x8*)(src);
      s16x8 v1 = *(const s16x8*)(src + 8);
#pragma unroll
      for (int e = 0; e < 8; ++e) {
        int d = c0 + e;
        *(short*)(Vts + d * 128 + ((r * 2) ^ ((d & 7) << 4))) = v0[e];
        int d2 = c0 + 8 + e;
        *(short*)(Vts + d2 * 128 + ((r * 2) ^ ((d2 & 7) << 4))) = v1[e];
      }
    }
    // stage mask words: Mw[qrow][w]
    {
      int qr = tid >> 1, w = tid & 1;
      Mw[qr * 2 + w] = mbits[(size_t)(qt * 128 + qr) * (Tn / 32) + kt * 2 + w];
    }
    __syncthreads();

    // ---- S = Q K^T : sacc[m][n], q row = m*16+lg*4+reg, k col = n*16+l15 ----
    f32x4 sacc[2][4];
#pragma unroll
    for (int m = 0; m < 2; ++m)
#pragma unroll
      for (int n = 0; n < 4; ++n) sacc[m][n] = f32x4{0.f, 0.f, 0.f, 0.f};
#pragma unroll
    for (int kk = 0; kk < 64; kk += 32) {
      s16x8 a[2], bb[4];
#pragma unroll
      for (int m = 0; m < 2; ++m) {
        int ra = wid * 32 + m * 16 + l15;
        a[m] = *(const s16x8*)(Qs + ra * 128 + (((kk + lg * 8) * 2) ^ ((ra & 7) << 4)));
      }
#pragma unroll
      for (int n = 0; n < 4; ++n) {
        int rb = n * 16 + l15;
        bb[n] = *(const s16x8*)(Ks + rb * 128 + (((kk + lg * 8) * 2) ^ ((rb & 7) << 4)));
      }
#pragma unroll
      for (int m = 0; m < 2; ++m)
#pragma unroll
        for (int n = 0; n < 4; ++n)
          sacc[m][n] = __builtin_amdgcn_mfma_f32_16x16x32_bf16(a[m], bb[n], sacc[m][n], 0, 0, 0);
    }

    // ---- no-max softmax (masked logit -> 0 -> p=1) + P write (R1-validated indexing) ----
#pragma unroll
    for (int m = 0; m < 2; ++m) {
#pragma unroll
      for (int q = 0; q < 4; ++q) {
        int rloc = m * 16 + lg * 4 + q;     // wave-local q row
        int qr = wid * 32 + rloc;           // block-local
        unsigned w0 = Mw[qr * 2], w1 = Mw[qr * 2 + 1];
        float psum = 0.0f;
#pragma unroll
        for (int n = 0; n < 4; ++n) {
          int kl = n * 16 + l15;
          unsigned wm_ = (n < 2) ? w0 : w1;
          float t = ((wm_ >> (kl & 31)) & 1u) ? sacc[m][n][q] * SCALE : 0.0f;
          float pv = __expf(t);
          psum += pv;
          union { float f; unsigned u; } c; c.f = pv;
          // truncating bf16 (bias ~2^-10 rel; provably negligible vs threshold)
          *(short*)(Pw + rloc * 128 + ((kl * 2) ^ ((rloc & 7) << 4))) = (short)(c.u >> 16);
        }
        lsum[m * 4 + q] += psum;
      }
    }
    // keep compiler from hoisting PV ds_reads above P ds_writes
    asm volatile("" ::: "memory");

    // ---- O += P V ----
#pragma unroll
    for (int kk = 0; kk < 64; kk += 32) {
      s16x8 pa[2], vb[4];
#pragma unroll
      for (int m = 0; m < 2; ++m) {
        int rp = m * 16 + l15;
        pa[m] = *(const s16x8*)(Pw + rp * 128 + (((kk + lg * 8) * 2) ^ ((rp & 7) << 4)));
      }
#pragma unroll
      for (int n = 0; n < 4; ++n) {
        int rv = n * 16 + l15;
        vb[n] = *(const s16x8*)(Vts + rv * 128 + (((kk + lg * 8) * 2) ^ ((rv & 7) << 4)));
      }
#pragma unroll
      for (int m = 0; m < 2; ++m)
#pragma unroll
        for (int n = 0; n < 4; ++n)
          oacc[m][n] = __builtin_amdgcn_mfma_f32_16x16x32_bf16(pa[m], vb[n], oacc[m][n], 0, 0, 0);
    }
    __syncthreads();
  }

  // ---- deferred denominator: butterfly over l15 (lanes sharing a q-row), then write ----
#pragma unroll
  for (int m = 0; m < 2; ++m)
#pragma unroll
    for (int q = 0; q < 4; ++q) {
      int si = m * 4 + q;
      float v = lsum[si];
      v += __shfl_xor(v, 1);
      v += __shfl_xor(v, 2);
      v += __shfl_xor(v, 4);
      v += __shfl_xor(v, 8);
      float inv = 1.0f / v;
      int rg = qt * 128 + wid * 32 + m * 16 + lg * 4 + q;
#pragma unroll
      for (int n = 0; n < 4; ++n)
        Og[(rowbase + rg) * Cn + cbase + n * 16 + l15] = f2bf(oacc[m][n][q] * inv);
    }
}

// ---------- host ----------
extern "C" void kernel_launch(void* const* d_in, const int* in_sizes, int n_in,
                              void* d_out, int out_size, void* d_ws, size_t ws_size,
                              hipStream_t stream) {
  (void)in_sizes; (void)n_in; (void)out_size; (void)ws_size;
  const float* query = (const float*)d_in[0];
  const float* key_  = (const float*)d_in[1];
  const float* value = (const float*)d_in[2];
  const int*   mask  = (const int*)d_in[3];
  const float* Wq = (const float*)d_in[4];
  const float* Wk = (const float*)d_in[5];
  const float* Wv = (const float*)d_in[6];
  const float* Wp = (const float*)d_in[7];
  const float* bp = (const float*)d_in[8];

  char* ws = (char*)d_ws;
  const size_t SX = (size_t)Mn * Cn * 2;   // 16 MiB
  const size_t SW = (size_t)Cn * Cn * 2;   // 2 MiB
  unsigned short* Xq  = (unsigned short*)(ws);
  unsigned short* Xk  = (unsigned short*)(ws + SX);
  unsigned short* Xv  = (unsigned short*)(ws + 2 * SX);
  unsigned short* Wqb = (unsigned short*)(ws + 3 * SX);
  unsigned short* Wkb = (unsigned short*)(ws + 3 * SX + SW);
  unsigned short* Wvb = (unsigned short*)(ws + 3 * SX + 2 * SW);
  unsigned short* Wpb = (unsigned short*)(ws + 3 * SX + 3 * SW);
  unsigned short* Qb  = (unsigned short*)(ws + 3 * SX + 4 * SW);
  unsigned short* Kb  = (unsigned short*)(ws + 4 * SX + 4 * SW);
  unsigned short* Vb  = (unsigned short*)(ws + 5 * SX + 4 * SW);
  unsigned*       mb  = (unsigned*)(ws + 6 * SX + 4 * SW);
  unsigned short* AO  = Xq;  // alias: Xq dead after Q-projection GEMM

  const int nX4 = Mn * Cn / 4, nW4 = Cn * Cn / 4;
  k_cvt<<<dim3(nX4 / 256), dim3(256), 0, stream>>>(query, Xq, nX4);
  k_cvt<<<dim3(nX4 / 256), dim3(256), 0, stream>>>(key_,  Xk, nX4);
  k_cvt<<<dim3(nX4 / 256), dim3(256), 0, stream>>>(value, Xv, nX4);
  k_cvt<<<dim3(nW4 / 256), dim3(256), 0, stream>>>(Wq, Wqb, nW4);
  k_cvt<<<dim3(nW4 / 256), dim3(256), 0, stream>>>(Wk, Wkb, nW4);
  k_cvt<<<dim3(nW4 / 256), dim3(256), 0, stream>>>(Wv, Wvb, nW4);
  k_cvt<<<dim3(nW4 / 256), dim3(256), 0, stream>>>(Wp, Wpb, nW4);
  k_pack<<<dim3((Tn * Tn) / 256), dim3(256), 0, stream>>>(mask, mb);

  dim3 gg(Cn / 128, Mn / 128);  // (8, 64)
  k_gemm<false><<<gg, dim3(256), 0, stream>>>(Xq, Wqb, Qb, nullptr, Mn, Cn, Cn);
  k_gemm<false><<<gg, dim3(256), 0, stream>>>(Xk, Wkb, Kb, nullptr, Mn, Cn, Cn);
  k_gemm<false><<<gg, dim3(256), 0, stream>>>(Xv, Wvb, Vb, nullptr, Mn, Cn, Cn);

  k_attn<<<dim3(Tn / 128, Bn * Hn), dim3(256), 0, stream>>>(Qb, Kb, Vb, mb, AO);

  k_gemm<true><<<gg, dim3(256), 0, stream>>>(AO, Wpb, d_out, bp, Mn, Cn, Cn);
}